// Round 3
// baseline (367.882 us; speedup 1.0000x reference)
//
#include <hip/hip_runtime.h>
#include <hip/hip_bf16.h>

// DCNv2 CrossNet on MI355X — fused 3-layer kernel, v7.
// Key change vs v6: trade TLP for ILP. v6 (BT=16, launch_bounds(512,8))
// compiled to 32 VGPRs -> each wave could hold ~4 outstanding loads ->
// barrier-convoyed waves stalled together on L2 latency (issue util 23%,
// all BW counters <17%). v7: BT=32/MT=2 (halves weight-fragment traffic vs
// v6), __launch_bounds__(512,4) -> 128 VGPRs/wave, 2 blocks/CU, grid 1024
// = exactly 2 residency rounds (no v5-style 1.33-round tail). Deeply
// unrolled K-loops let the compiler keep 8-16 weight loads in flight.
// Also: separate z_s buffer removes GEMM2's in-place barrier (4->3
// barriers/layer); GEMM3 merged to one nt=0..3 pass (acc3=32 VGPRs, A-reads
// once). Padded (non-XOR) LDS layouts kept (+8-short pad, conflict-free).
//
// Shapes: x[32768,512]; Vs[3,4,64,512]; Cs[3,4,64,64]; Us[3,4,512,64];
//         bias[3,512]; gate_w[512,4].

#define CROSS   3
#define ENUM    4
#define LR      64
#define ELD     256     // ENUM*LR
#define DIM     512
#define BATCH   32768
#define BT      32      // batch rows per block
#define MT      2       // row-tiles (16 rows each) per thread
#define NTHR    512     // 8 waves

#define XL_W    520     // 512 + 8 pad (shorts)
#define Y_W     264     // 256 + 8 pad (shorts)

typedef __bf16 bf16x8 __attribute__((ext_vector_type(8)));
typedef float  f32x4  __attribute__((ext_vector_type(4)));
typedef unsigned short us;
typedef unsigned short us4 __attribute__((ext_vector_type(4)));

__device__ __forceinline__ us f2bf(float f) {
    return __builtin_bit_cast(us, (__bf16)f);
}
__device__ __forceinline__ float bf2f(us b) {
    unsigned int u = ((unsigned int)b) << 16;
    return __builtin_bit_cast(float, u);
}
// fast tanh: (e^2x - 1) / (e^2x + 1); inputs bounded by 0.05-scaled weights.
__device__ __forceinline__ float tanh_fast(float x) {
    float t = __expf(2.f * x);
    return (t - 1.f) * __builtin_amdgcn_rcpf(t + 1.f);
}

#define MFMA(a, b, c) __builtin_amdgcn_mfma_f32_16x16x32_bf16(a, b, c, 0, 0, 0)

// ---------------------------------------------------------------------------
// Swizzle prepass: fp32 weights -> bf16 MFMA-B fragment order
// frag[nt][ks][lane][8]: n = nt*16 + (lane&15), k = ks*32 + (lane>>4)*8 + j.
// ---------------------------------------------------------------------------
__global__ __launch_bounds__(64) void swz_all(
    const float* __restrict__ Vs, const float* __restrict__ Cs,
    const float* __restrict__ Us, const float* __restrict__ gw,
    us* __restrict__ Vf, us* __restrict__ Cf,
    us* __restrict__ Uf, us* __restrict__ Gf)
{
    int b = blockIdx.x;
    int lane = threadIdx.x;
    if (b < 768) {                       // V: [3][16 nt][16 ks]
        int i = b >> 8, t = b & 255;
        int nt = t >> 4, ks = t & 15;
        int n  = nt * 16 + (lane & 15);
        int k0 = ks * 32 + (lane >> 4) * 8;
        const float* src = Vs + (size_t)i * ELD * DIM + (size_t)n * DIM + k0;
        us* dst = Vf + (size_t)i * ELD * DIM
                + ((size_t)(nt * 16 + ks) * 64 + lane) * 8;
        #pragma unroll
        for (int j = 0; j < 8; ++j) dst[j] = f2bf(src[j]);
    } else if (b < 1536) {               // U': [3][32 nt][8 ks], k = e*64+l
        int bb = b - 768;
        int i = bb >> 8, t = bb & 255;
        int nt = t >> 3, ks = t & 7;
        int n  = nt * 16 + (lane & 15);            // d
        int k0 = ks * 32 + (lane >> 4) * 8;        // e*64 + l
        int e = k0 >> 6, l0 = k0 & 63;
        const float* src = Us + (size_t)i * ENUM * DIM * LR
                         + (size_t)e * DIM * LR + (size_t)n * LR + l0;
        us* dst = Uf + (size_t)i * DIM * ELD
                + ((size_t)(nt * 8 + ks) * 64 + lane) * 8;
        #pragma unroll
        for (int j = 0; j < 8; ++j) dst[j] = f2bf(src[j]);
    } else if (b < 1632) {               // C: [3][4 e][4 nt][2 ks]
        int bb = b - 1536;
        int i = bb >> 5, rest = bb & 31;
        int e = rest >> 3, t = rest & 7;
        int nt = t >> 1, ks = t & 1;
        int n  = nt * 16 + (lane & 15);
        int k0 = ks * 32 + (lane >> 4) * 8;
        const float* src = Cs + (((size_t)(i * ENUM + e) * LR + n) * LR) + k0;
        us* dst = Cf + (size_t)i * ENUM * LR * LR
                + ((size_t)((e * 4 + nt) * 2 + ks) * 64 + lane) * 8;
        #pragma unroll
        for (int j = 0; j < 8; ++j) dst[j] = f2bf(src[j]);
    } else {                             // gate: [16 ks], n<4 real, rest 0
        int ks = b - 1632;
        int n  = lane & 15;
        int k0 = ks * 32 + (lane >> 4) * 8;
        us* dst = Gf + ((size_t)ks * 64 + lane) * 8;
        #pragma unroll
        for (int j = 0; j < 8; ++j)
            dst[j] = (n < ENUM) ? f2bf(gw[(size_t)(k0 + j) * ENUM + n]) : (us)0;
    }
}

// ---------------------------------------------------------------------------
// Fused 3-layer kernel. Block: 32 rows, 512 threads (8 waves), 2 blocks/CU.
// Thread element ownership (16x16x32 D-layout, mt in 0..1):
//   row = mt*16 + quad*4 + r,  col(G3) = wave*64 + nt*16 + nl.
// G1: wave owns cols [wave*32,+32) (nt_r=2); wave 0 additionally folds the
// gate GEMM in as one extra B-fragment. G2: expert e = wave>>1, col-half
// h = wave&1, output -> z_s (separate buffer, no pre-write barrier).
// G3: wave owns cols [wave*64,+64) (nt_r=4) in one pass, A from z_s.
// ---------------------------------------------------------------------------
__global__ __launch_bounds__(NTHR, 4) void dcn_fused(
    const float* __restrict__ x,
    float* __restrict__ out,
    const us* __restrict__ Vf,
    const us* __restrict__ Cf,
    const us* __restrict__ Uf,
    const us* __restrict__ Gf,
    const float* __restrict__ bias)
{
    __shared__ us xl_s[BT * XL_W];       // x_l master, bf16 (33.3 KB)
    __shared__ us y_s[BT * Y_W];         // Y (16.9 KB)
    __shared__ us z_s[BT * Y_W];         // z (16.9 KB)
    __shared__ float g_s[BT * ENUM];     // gate scores (0.5 KB)

    const int tid  = threadIdx.x;
    const int wave = tid >> 6, lane = tid & 63;
    const int quad = lane >> 4, nl = lane & 15;
    const int row0 = blockIdx.x * BT;

    // ---- stage x -> xl_s (bf16): 32*128 = 4096 float4s, 8 per thread
    #pragma unroll
    for (int it = 0; it < 8; ++it) {
        int f4 = tid + it * NTHR;            // 0..4095
        int r = f4 >> 7, c4 = f4 & 127;
        float4 v = *reinterpret_cast<const float4*>(
            x + (size_t)(row0 + r) * DIM + c4 * 4);
        us4 p;
        p[0] = f2bf(v.x); p[1] = f2bf(v.y); p[2] = f2bf(v.z); p[3] = f2bf(v.w);
        *reinterpret_cast<us4*>(&xl_s[r * XL_W + c4 * 4]) = p;
    }
    __syncthreads();

    // ---- x0 packed bf16 in regs (thread's ownership elements)
    unsigned int x0p[MT][4][2];
    #pragma unroll
    for (int mt = 0; mt < MT; ++mt)
        #pragma unroll
        for (int nt = 0; nt < 4; ++nt) {
            int rb = mt * 16 + quad * 4;
            int col = wave * 64 + nt * 16 + nl;
            unsigned int b0 = xl_s[(rb + 0) * XL_W + col];
            unsigned int b1 = xl_s[(rb + 1) * XL_W + col];
            unsigned int b2 = xl_s[(rb + 2) * XL_W + col];
            unsigned int b3 = xl_s[(rb + 3) * XL_W + col];
            x0p[mt][nt][0] = b0 | (b1 << 16);
            x0p[mt][nt][1] = b2 | (b3 << 16);
        }

    #pragma unroll 1
    for (int layer = 0; layer < CROSS; ++layer) {
        const us* Vl = Vf + (size_t)layer * ELD * DIM;
        const us* Cl = Cf + (size_t)layer * ENUM * LR * LR;
        const us* Ul = Uf + (size_t)layer * DIM * ELD;
        const float* bl = bias + layer * DIM;

        // ---- GEMM1: Y = tanh(xl @ V^T), wave cols [wave*32,+32); wave 0: gate
        f32x4 acc1[MT][2];
        f32x4 gacc[MT];
        #pragma unroll
        for (int mt = 0; mt < MT; ++mt) {
            gacc[mt] = (f32x4)0.f;
            acc1[mt][0] = (f32x4)0.f;
            acc1[mt][1] = (f32x4)0.f;
        }
        #pragma unroll 8
        for (int ks = 0; ks < 16; ++ks) {
            bf16x8 a[MT];
            #pragma unroll
            for (int mt = 0; mt < MT; ++mt)
                a[mt] = *reinterpret_cast<const bf16x8*>(
                    &xl_s[(mt * 16 + nl) * XL_W + ks * 32 + quad * 8]);
            #pragma unroll
            for (int nt = 0; nt < 2; ++nt) {
                bf16x8 bfr = *reinterpret_cast<const bf16x8*>(
                    &Vl[((size_t)((wave * 2 + nt) * 16 + ks) * 64 + lane) * 8]);
                #pragma unroll
                for (int mt = 0; mt < MT; ++mt)
                    acc1[mt][nt] = MFMA(a[mt], bfr, acc1[mt][nt]);
            }
            if (wave == 0) {
                bf16x8 bg = *reinterpret_cast<const bf16x8*>(
                    &Gf[((size_t)ks * 64 + lane) * 8]);
                #pragma unroll
                for (int mt = 0; mt < MT; ++mt)
                    gacc[mt] = MFMA(a[mt], bg, gacc[mt]);
            }
        }
        #pragma unroll
        for (int mt = 0; mt < MT; ++mt)
            #pragma unroll
            for (int r = 0; r < 4; ++r) {
                int row = mt * 16 + quad * 4 + r;
                #pragma unroll
                for (int nt = 0; nt < 2; ++nt)
                    y_s[row * Y_W + wave * 32 + nt * 16 + nl] =
                        f2bf(tanh_fast(acc1[mt][nt][r]));
            }
        if (wave == 0 && nl < ENUM) {
            #pragma unroll
            for (int mt = 0; mt < MT; ++mt)
                #pragma unroll
                for (int r = 0; r < 4; ++r)
                    g_s[(mt * 16 + quad * 4 + r) * ENUM + nl] = gacc[mt][r];
        }
        __syncthreads();

        // ---- GEMM2: z = g ⊙ tanh(Y_e @ C_e^T) -> z_s. e = wave>>1, h = wave&1.
        const int e = wave >> 1, h = wave & 1;
        f32x4 acc2[MT][2];
        #pragma unroll
        for (int mt = 0; mt < MT; ++mt) {
            acc2[mt][0] = (f32x4)0.f;
            acc2[mt][1] = (f32x4)0.f;
        }
        #pragma unroll
        for (int ks = 0; ks < 2; ++ks) {
            bf16x8 a[MT];
            #pragma unroll
            for (int mt = 0; mt < MT; ++mt)
                a[mt] = *reinterpret_cast<const bf16x8*>(
                    &y_s[(mt * 16 + nl) * Y_W + e * 64 + ks * 32 + quad * 8]);
            #pragma unroll
            for (int nt = 0; nt < 2; ++nt) {
                bf16x8 bfr = *reinterpret_cast<const bf16x8*>(
                    &Cl[((size_t)((e * 4 + h * 2 + nt) * 2 + ks) * 64 + lane) * 8]);
                #pragma unroll
                for (int mt = 0; mt < MT; ++mt)
                    acc2[mt][nt] = MFMA(a[mt], bfr, acc2[mt][nt]);
            }
        }
        // z goes to z_s (separate buffer) — no pre-write barrier needed.
        #pragma unroll
        for (int mt = 0; mt < MT; ++mt)
            #pragma unroll
            for (int r = 0; r < 4; ++r) {
                int row = mt * 16 + quad * 4 + r;
                float gv = g_s[row * ENUM + e];
                #pragma unroll
                for (int nt = 0; nt < 2; ++nt)
                    z_s[row * Y_W + e * 64 + h * 32 + nt * 16 + nl] =
                        f2bf(tanh_fast(acc2[mt][nt][r]) * gv);
            }
        __syncthreads();

        // ---- Gv = sum_e g[row][e]
        float Gv[MT][4];
        #pragma unroll
        for (int mt = 0; mt < MT; ++mt)
            #pragma unroll
            for (int r = 0; r < 4; ++r) {
                int row = mt * 16 + quad * 4 + r;
                f32x4 g4 = *reinterpret_cast<const f32x4*>(&g_s[row * ENUM]);
                Gv[mt][r] = g4[0] + g4[1] + g4[2] + g4[3];
            }

        // ---- GEMM3: core = z @ U'^T, wave cols [wave*64,+64), K=256,
        // single nt=0..3 pass (acc3 = 32 VGPRs; A-fragments read once).
        f32x4 acc3[MT][4];
        #pragma unroll
        for (int mt = 0; mt < MT; ++mt)
            #pragma unroll
            for (int nt = 0; nt < 4; ++nt) acc3[mt][nt] = (f32x4)0.f;
        #pragma unroll
        for (int ks = 0; ks < 8; ++ks) {
            bf16x8 a[MT];
            #pragma unroll
            for (int mt = 0; mt < MT; ++mt)
                a[mt] = *reinterpret_cast<const bf16x8*>(
                    &z_s[(mt * 16 + nl) * Y_W + ks * 32 + quad * 8]);
            #pragma unroll
            for (int nt = 0; nt < 4; ++nt) {
                bf16x8 bfr = *reinterpret_cast<const bf16x8*>(
                    &Ul[((size_t)((wave * 4 + nt) * 8 + ks) * 64 + lane) * 8]);
                #pragma unroll
                for (int mt = 0; mt < MT; ++mt)
                    acc3[mt][nt] = MFMA(a[mt], bfr, acc3[mt][nt]);
            }
        }

        // ---- epilogue: xl = xl + x0 * (core + bias*G)
        #pragma unroll
        for (int nt = 0; nt < 4; ++nt) {
            int col = wave * 64 + nt * 16 + nl;
            float bc = bl[col];
            #pragma unroll
            for (int mt = 0; mt < MT; ++mt)
                #pragma unroll
                for (int r = 0; r < 4; ++r) {
                    int row = mt * 16 + quad * 4 + r;
                    float x0v = bf2f(
                        (us)(x0p[mt][nt][r >> 1] >> ((r & 1) * 16)));
                    float xlo = bf2f(xl_s[row * XL_W + col]);
                    float res = xlo
                              + x0v * (acc3[mt][nt][r] + bc * Gv[mt][r]);
                    if (layer == CROSS - 1)
                        out[(size_t)(row0 + row) * DIM + col] = res;
                    else
                        xl_s[row * XL_W + col] = f2bf(res);
                }
        }
        if (layer < CROSS - 1) __syncthreads();
    }
}

// ---------------------------------------------------------------------------
extern "C" void kernel_launch(void* const* d_in, const int* in_sizes, int n_in,
                              void* d_out, int out_size, void* d_ws,
                              size_t ws_size, hipStream_t stream) {
    const float* x      = (const float*)d_in[0];
    const float* Vs     = (const float*)d_in[1];
    const float* Cs     = (const float*)d_in[2];
    const float* Us     = (const float*)d_in[3];
    const float* bias   = (const float*)d_in[4];
    const float* gate_w = (const float*)d_in[5];
    float* out = (float*)d_out;

    us* Vf = (us*)d_ws;                                   // 393216 bf16
    us* Uf = Vf + (size_t)CROSS * ELD * DIM;              // 393216
    us* Cf = Uf + (size_t)CROSS * DIM * ELD;              // 49152
    us* Gf = Cf + (size_t)CROSS * ENUM * LR * LR;         // 8192

    swz_all<<<1648, 64, 0, stream>>>(Vs, Cs, Us, gate_w, Vf, Cf, Uf, Gf);
    dcn_fused<<<BATCH / BT, NTHR, 0, stream>>>(x, out, Vf, Cf, Uf, Gf, bias);
}

// Round 4
// 318.115 us; speedup vs baseline: 1.1564x; 1.1564x over previous
//
#include <hip/hip_runtime.h>
#include <hip/hip_bf16.h>

// DCNv2 CrossNet on MI355X — fused 3-layer kernel, v8.
// Structural change vs v4-v7: weights are bulk-staged into LDS via
// __builtin_amdgcn_global_load_lds (width 16) instead of streamed
// global->VGPR inside the MFMA loops. Four rounds of counters showed issue
// util pinned at 20-25% at ANY occupancy: register-resident weight loads
// can't hold enough outstanding requests (need ~100/SIMD at L2 latency,
// have ~20). LDS staging moves the latency problem to bulk async copies
// (no VGPR cost, deep pipelining) and the inner loop to ds_read_b128.
// Config: BT=64 rows, 1024 threads (16 waves, 4/SIMD), 1 block/CU,
// grid 512 = exactly 2 residency rounds. LDS 131 KB: xl 66.6 + y/z 33.8 +
// 32 KB weight stage + 1 KB gate. V double-buffered in 16 KB ks-slices;
// U staged per-ks as 32 KB slices (first slice hidden behind GEMM2).
// C (tiny) prefetched to registers at layer start; gate read direct.
//
// Shapes: x[32768,512]; Vs[3,4,64,512]; Cs[3,4,64,64]; Us[3,4,512,64];
//         bias[3,512]; gate_w[512,4].

#define CROSS   3
#define ENUM    4
#define LR      64
#define ELD     256     // ENUM*LR
#define DIM     512
#define BATCH   32768
#define BT      64      // batch rows per block
#define NTHR    1024    // 16 waves

#define XL_W    520     // 512 + 8 pad (shorts)
#define Y_W     264     // 256 + 8 pad (shorts)

typedef __bf16 bf16x8 __attribute__((ext_vector_type(8)));
typedef float  f32x4  __attribute__((ext_vector_type(4)));
typedef unsigned short us;
typedef unsigned short us4 __attribute__((ext_vector_type(4)));

__device__ __forceinline__ us f2bf(float f) {
    return __builtin_bit_cast(us, (__bf16)f);
}
__device__ __forceinline__ float bf2f(us b) {
    unsigned int u = ((unsigned int)b) << 16;
    return __builtin_bit_cast(float, u);
}
// fast tanh: (e^2x - 1) / (e^2x + 1); inputs bounded by 0.05-scaled weights.
__device__ __forceinline__ float tanh_fast(float x) {
    float t = __expf(2.f * x);
    return (t - 1.f) * __builtin_amdgcn_rcpf(t + 1.f);
}

#define MFMA(a, b, c) __builtin_amdgcn_mfma_f32_16x16x32_bf16(a, b, c, 0, 0, 0)

// async global->LDS copy, 16 B per lane. lds dest must be wave-uniform;
// HW writes lane l at dst + l*16.
__device__ __forceinline__ void gload_lds16(const us* g, us* l) {
    __builtin_amdgcn_global_load_lds(
        (const __attribute__((address_space(1))) unsigned int*)g,
        (__attribute__((address_space(3))) unsigned int*)l, 16, 0, 0);
}

// ---------------------------------------------------------------------------
// Swizzle prepass: fp32 weights -> bf16 MFMA-B fragment order
// frag[nt][ks][lane][8]: n = nt*16 + (lane&15), k = ks*32 + (lane>>4)*8 + j.
// ---------------------------------------------------------------------------
__global__ __launch_bounds__(64) void swz_all(
    const float* __restrict__ Vs, const float* __restrict__ Cs,
    const float* __restrict__ Us, const float* __restrict__ gw,
    us* __restrict__ Vf, us* __restrict__ Cf,
    us* __restrict__ Uf, us* __restrict__ Gf)
{
    int b = blockIdx.x;
    int lane = threadIdx.x;
    if (b < 768) {                       // V: [3][16 nt][16 ks]
        int i = b >> 8, t = b & 255;
        int nt = t >> 4, ks = t & 15;
        int n  = nt * 16 + (lane & 15);
        int k0 = ks * 32 + (lane >> 4) * 8;
        const float* src = Vs + (size_t)i * ELD * DIM + (size_t)n * DIM + k0;
        us* dst = Vf + (size_t)i * ELD * DIM
                + ((size_t)(nt * 16 + ks) * 64 + lane) * 8;
        #pragma unroll
        for (int j = 0; j < 8; ++j) dst[j] = f2bf(src[j]);
    } else if (b < 1536) {               // U': [3][32 nt][8 ks], k = e*64+l
        int bb = b - 768;
        int i = bb >> 8, t = bb & 255;
        int nt = t >> 3, ks = t & 7;
        int n  = nt * 16 + (lane & 15);            // d
        int k0 = ks * 32 + (lane >> 4) * 8;        // e*64 + l
        int e = k0 >> 6, l0 = k0 & 63;
        const float* src = Us + (size_t)i * ENUM * DIM * LR
                         + (size_t)e * DIM * LR + (size_t)n * LR + l0;
        us* dst = Uf + (size_t)i * DIM * ELD
                + ((size_t)(nt * 8 + ks) * 64 + lane) * 8;
        #pragma unroll
        for (int j = 0; j < 8; ++j) dst[j] = f2bf(src[j]);
    } else if (b < 1632) {               // C: [3][4 e][4 nt][2 ks]
        int bb = b - 1536;
        int i = bb >> 5, rest = bb & 31;
        int e = rest >> 3, t = rest & 7;
        int nt = t >> 1, ks = t & 1;
        int n  = nt * 16 + (lane & 15);
        int k0 = ks * 32 + (lane >> 4) * 8;
        const float* src = Cs + (((size_t)(i * ENUM + e) * LR + n) * LR) + k0;
        us* dst = Cf + (size_t)i * ENUM * LR * LR
                + ((size_t)((e * 4 + nt) * 2 + ks) * 64 + lane) * 8;
        #pragma unroll
        for (int j = 0; j < 8; ++j) dst[j] = f2bf(src[j]);
    } else {                             // gate: [16 ks], n<4 real, rest 0
        int ks = b - 1632;
        int n  = lane & 15;
        int k0 = ks * 32 + (lane >> 4) * 8;
        us* dst = Gf + ((size_t)ks * 64 + lane) * 8;
        #pragma unroll
        for (int j = 0; j < 8; ++j)
            dst[j] = (n < ENUM) ? f2bf(gw[(size_t)(k0 + j) * ENUM + n]) : (us)0;
    }
}

// ---------------------------------------------------------------------------
// Fused 3-layer kernel. Block: 64 rows, 1024 threads (16 waves), 1 block/CU.
// Wave split: rh = wave>>3 (row half, 32 rows), wc = wave&7 (col group).
// Thread element ownership (16x16x32 D-layout, mt in 0..1):
//   row = rh*32 + mt*16 + quad*4 + r,  col(G3) = wc*64 + nt*16 + nl.
// G1: wc owns cols [wc*32,+32) of Y (nt_r=2); wc==0 waves fold the gate in.
// G2: expert e = wc>>1, col-half h = wc&1; C-frags from registers.
// G3: wc owns cols [wc*64,+64) (nt_r=4), U staged per-ks (32 KB slices).
// Weight staging: wave w loads fragment nt_g = w (V) or {w, w+16} (U) of the
// current ks-slice; LDS dest = wave-uniform base + lane*16 (linear order).
// ---------------------------------------------------------------------------
__global__ __launch_bounds__(NTHR, 4) void dcn_fused(
    const float* __restrict__ x,
    float* __restrict__ out,
    const us* __restrict__ Vf,
    const us* __restrict__ Cf,
    const us* __restrict__ Uf,
    const us* __restrict__ Gf,
    const float* __restrict__ bias)
{
    __shared__ us xl_s[BT * XL_W];       // x_l master, bf16 (66.6 KB)
    __shared__ us y_s[BT * Y_W];         // Y then z, in place (33.8 KB)
    __shared__ us wst[16384];            // weight stage, 32 KB
    __shared__ float g_s[BT * ENUM];     // gate scores (1 KB)

    const int tid  = threadIdx.x;
    const int wave = tid >> 6, lane = tid & 63;
    const int quad = lane >> 4, nl = lane & 15;
    const int rh = wave >> 3, wc = wave & 7;
    const int rh32 = rh * 32;
    const int row0 = blockIdx.x * BT;

    // ---- stage x -> xl_s (bf16): 64*128 = 8192 float4s, 8 per thread
    #pragma unroll
    for (int it = 0; it < 8; ++it) {
        int f4 = tid + it * NTHR;            // 0..8191
        int r = f4 >> 7, c4 = f4 & 127;
        float4 v = *reinterpret_cast<const float4*>(
            x + (size_t)(row0 + r) * DIM + c4 * 4);
        us4 p;
        p[0] = f2bf(v.x); p[1] = f2bf(v.y); p[2] = f2bf(v.z); p[3] = f2bf(v.w);
        *reinterpret_cast<us4*>(&xl_s[r * XL_W + c4 * 4]) = p;
    }
    __syncthreads();

    // ---- x0 packed bf16 in regs (thread's ownership elements)
    unsigned int x0p[2][4][2];
    #pragma unroll
    for (int mt = 0; mt < 2; ++mt)
        #pragma unroll
        for (int nt = 0; nt < 4; ++nt) {
            int rb = rh32 + mt * 16 + quad * 4;
            int col = wc * 64 + nt * 16 + nl;
            unsigned int b0 = xl_s[(rb + 0) * XL_W + col];
            unsigned int b1 = xl_s[(rb + 1) * XL_W + col];
            unsigned int b2 = xl_s[(rb + 2) * XL_W + col];
            unsigned int b3 = xl_s[(rb + 3) * XL_W + col];
            x0p[mt][nt][0] = b0 | (b1 << 16);
            x0p[mt][nt][1] = b2 | (b3 << 16);
        }

    const int e = wc >> 1, h = wc & 1;   // GEMM2 roles

    #pragma unroll 1
    for (int layer = 0; layer < CROSS; ++layer) {
        const us* Vl = Vf + (size_t)layer * ELD * DIM;
        const us* Cl = Cf + (size_t)layer * ENUM * LR * LR;
        const us* Ul = Uf + (size_t)layer * DIM * ELD;
        const float* bl = bias + layer * DIM;

        // ---- prefetch C fragments for GEMM2 (4 x 16 B, stay in VGPRs)
        bf16x8 creg[2][2];
        #pragma unroll
        for (int ks = 0; ks < 2; ++ks)
            #pragma unroll
            for (int nt = 0; nt < 2; ++nt)
                creg[ks][nt] = *reinterpret_cast<const bf16x8*>(
                    &Cl[((size_t)((e * 4 + h * 2 + nt) * 2 + ks) * 64 + lane) * 8]);

        // ---- stage V ks=0 slice (16 KB): wave w loads fragment nt_g = w
        gload_lds16(Vl + ((size_t)(wave * 16 + 0) * 64 + lane) * 8,
                    wst + wave * 512);
        __syncthreads();   // publishes xl_s (init / prev epilogue) + drains

        // ---- GEMM1: Y = tanh(xl @ V^T); V double-buffered per ks
        f32x4 acc1[2][2];
        f32x4 gacc[2];
        #pragma unroll
        for (int mt = 0; mt < 2; ++mt) {
            gacc[mt] = (f32x4)0.f;
            acc1[mt][0] = (f32x4)0.f;
            acc1[mt][1] = (f32x4)0.f;
        }
        #pragma unroll 2
        for (int ks = 0; ks < 16; ++ks) {
            if (ks < 15)
                gload_lds16(Vl + ((size_t)(wave * 16 + ks + 1) * 64 + lane) * 8,
                            wst + ((ks + 1) & 1) * 8192 + wave * 512);
            const us* vb = wst + (ks & 1) * 8192;
            bf16x8 a0 = *reinterpret_cast<const bf16x8*>(
                &xl_s[(rh32 + nl) * XL_W + ks * 32 + quad * 8]);
            bf16x8 a1 = *reinterpret_cast<const bf16x8*>(
                &xl_s[(rh32 + 16 + nl) * XL_W + ks * 32 + quad * 8]);
            #pragma unroll
            for (int nt = 0; nt < 2; ++nt) {
                bf16x8 bfr = *reinterpret_cast<const bf16x8*>(
                    &vb[(wc * 2 + nt) * 512 + lane * 8]);
                acc1[0][nt] = MFMA(a0, bfr, acc1[0][nt]);
                acc1[1][nt] = MFMA(a1, bfr, acc1[1][nt]);
            }
            if (wc == 0) {
                bf16x8 bg = *reinterpret_cast<const bf16x8*>(
                    &Gf[((size_t)ks * 64 + lane) * 8]);
                gacc[0] = MFMA(a0, bg, gacc[0]);
                gacc[1] = MFMA(a1, bg, gacc[1]);
            }
            if (ks < 15) __syncthreads();
        }
        // write Y + gate scores
        #pragma unroll
        for (int mt = 0; mt < 2; ++mt)
            #pragma unroll
            for (int r = 0; r < 4; ++r) {
                int row = rh32 + mt * 16 + quad * 4 + r;
                #pragma unroll
                for (int nt = 0; nt < 2; ++nt)
                    y_s[row * Y_W + wc * 32 + nt * 16 + nl] =
                        f2bf(tanh_fast(acc1[mt][nt][r]));
            }
        if (wc == 0 && nl < ENUM) {
            #pragma unroll
            for (int mt = 0; mt < 2; ++mt)
                #pragma unroll
                for (int r = 0; r < 4; ++r)
                    g_s[(rh32 + mt * 16 + quad * 4 + r) * ENUM + nl] =
                        gacc[mt][r];
        }
        __syncthreads();   // Y + g ready

        // ---- Gv = sum_e g[row][e] (g_s stable from here on)
        float Gv[2][4];
        #pragma unroll
        for (int mt = 0; mt < 2; ++mt)
            #pragma unroll
            for (int r = 0; r < 4; ++r) {
                int row = rh32 + mt * 16 + quad * 4 + r;
                f32x4 g4 = *reinterpret_cast<const f32x4*>(&g_s[row * ENUM]);
                Gv[mt][r] = g4[0] + g4[1] + g4[2] + g4[3];
            }

        // ---- GEMM2: z = g ⊙ tanh(Y_e @ C_e^T), C from registers
        f32x4 acc2[2][2];
        #pragma unroll
        for (int mt = 0; mt < 2; ++mt) {
            acc2[mt][0] = (f32x4)0.f;
            acc2[mt][1] = (f32x4)0.f;
        }
        #pragma unroll
        for (int ks = 0; ks < 2; ++ks) {
            bf16x8 a0 = *reinterpret_cast<const bf16x8*>(
                &y_s[(rh32 + nl) * Y_W + e * 64 + ks * 32 + quad * 8]);
            bf16x8 a1 = *reinterpret_cast<const bf16x8*>(
                &y_s[(rh32 + 16 + nl) * Y_W + e * 64 + ks * 32 + quad * 8]);
            #pragma unroll
            for (int nt = 0; nt < 2; ++nt) {
                acc2[0][nt] = MFMA(a0, creg[ks][nt], acc2[0][nt]);
                acc2[1][nt] = MFMA(a1, creg[ks][nt], acc2[1][nt]);
            }
        }
        // stage U ks=0 slice (32 KB) now: wst is free, latency hides here
        gload_lds16(Ul + ((size_t)(wave * 8 + 0) * 64 + lane) * 8,
                    wst + wave * 512);
        gload_lds16(Ul + ((size_t)((wave + 16) * 8 + 0) * 64 + lane) * 8,
                    wst + (wave + 16) * 512);
        __syncthreads();   // all Y reads complete (also drains U ks=0)
        #pragma unroll
        for (int mt = 0; mt < 2; ++mt)
            #pragma unroll
            for (int r = 0; r < 4; ++r) {
                int row = rh32 + mt * 16 + quad * 4 + r;
                float gv = g_s[row * ENUM + e];
                #pragma unroll
                for (int nt = 0; nt < 2; ++nt)
                    y_s[row * Y_W + e * 64 + h * 32 + nt * 16 + nl] =
                        f2bf(tanh_fast(acc2[mt][nt][r]) * gv);
            }
        __syncthreads();   // z ready (U ks=0 staged & visible)

        // ---- GEMM3: core = z @ U'^T, K=256, U staged per-ks (single buffer)
        f32x4 acc3[2][4];
        #pragma unroll
        for (int mt = 0; mt < 2; ++mt)
            #pragma unroll
            for (int nt = 0; nt < 4; ++nt) acc3[mt][nt] = (f32x4)0.f;
        #pragma unroll 1
        for (int ks = 0; ks < 8; ++ks) {
            if (ks > 0) {
                __syncthreads();   // all waves done reading slice ks-1
                gload_lds16(Ul + ((size_t)(wave * 8 + ks) * 64 + lane) * 8,
                            wst + wave * 512);
                gload_lds16(Ul + ((size_t)((wave + 16) * 8 + ks) * 64 + lane) * 8,
                            wst + (wave + 16) * 512);
                __syncthreads();   // slice ks staged & visible
            }
            bf16x8 a0 = *reinterpret_cast<const bf16x8*>(
                &y_s[(rh32 + nl) * Y_W + ks * 32 + quad * 8]);
            bf16x8 a1 = *reinterpret_cast<const bf16x8*>(
                &y_s[(rh32 + 16 + nl) * Y_W + ks * 32 + quad * 8]);
            #pragma unroll
            for (int nt = 0; nt < 4; ++nt) {
                bf16x8 bfr = *reinterpret_cast<const bf16x8*>(
                    &wst[(wc * 4 + nt) * 512 + lane * 8]);
                acc3[0][nt] = MFMA(a0, bfr, acc3[0][nt]);
                acc3[1][nt] = MFMA(a1, bfr, acc3[1][nt]);
            }
        }
        __syncthreads();   // wst free for next layer's V stage

        // ---- epilogue: xl = xl + x0 * (core + bias*G)
        #pragma unroll
        for (int nt = 0; nt < 4; ++nt) {
            int col = wc * 64 + nt * 16 + nl;
            float bc = bl[col];
            #pragma unroll
            for (int mt = 0; mt < 2; ++mt)
                #pragma unroll
                for (int r = 0; r < 4; ++r) {
                    int row = rh32 + mt * 16 + quad * 4 + r;
                    float x0v = bf2f(
                        (us)(x0p[mt][nt][r >> 1] >> ((r & 1) * 16)));
                    float xlo = bf2f(xl_s[row * XL_W + col]);
                    float res = xlo
                              + x0v * (acc3[mt][nt][r] + bc * Gv[mt][r]);
                    if (layer == CROSS - 1)
                        out[(size_t)(row0 + row) * DIM + col] = res;
                    else
                        xl_s[row * XL_W + col] = f2bf(res);
                }
        }
        // next layer's prologue barrier publishes xl_s
    }
}

// ---------------------------------------------------------------------------
extern "C" void kernel_launch(void* const* d_in, const int* in_sizes, int n_in,
                              void* d_out, int out_size, void* d_ws,
                              size_t ws_size, hipStream_t stream) {
    const float* x      = (const float*)d_in[0];
    const float* Vs     = (const float*)d_in[1];
    const float* Cs     = (const float*)d_in[2];
    const float* Us     = (const float*)d_in[3];
    const float* bias   = (const float*)d_in[4];
    const float* gate_w = (const float*)d_in[5];
    float* out = (float*)d_out;

    us* Vf = (us*)d_ws;                                   // 393216 bf16
    us* Uf = Vf + (size_t)CROSS * ELD * DIM;              // 393216
    us* Cf = Uf + (size_t)CROSS * DIM * ELD;              // 49152
    us* Gf = Cf + (size_t)CROSS * ENUM * LR * LR;         // 8192

    swz_all<<<1648, 64, 0, stream>>>(Vs, Cs, Us, gate_w, Vf, Cf, Uf, Gf);
    dcn_fused<<<BATCH / BT, NTHR, 0, stream>>>(x, out, Vf, Cf, Uf, Gf, bias);
}